// Round 3
// baseline (232.962 us; speedup 1.0000x reference)
//
#include <hip/hip_runtime.h>
#include <cmath>

// Problem constants (from reference setup_inputs)
#define B_  32
#define S_  52
#define A_  5
#define C_  80
#define T_  50
#define PD_ (A_ * (5 + C_))   // 425 channels per spatial cell

#define NCELLS   (B_ * S_ * S_)        // 86528 == 338 * 256 exactly
#define NCONFBLK (NCELLS / 256)        // 338
// ws layout (floats): [0..337] per-block conf^2 partials
//                     [338]=S_off [339]=S_scale [340]=S_obj [341]=S_conf2_winners

__constant__ float c_anchors[A_ * 2] = {
    1.3221f, 1.73145f,
    3.19275f, 4.00944f,
    5.05587f, 8.09892f,
    9.47112f, 4.84053f,
    11.2364f, 10.0071f
};

__device__ __forceinline__ float sigmoidf_(float x) {
    return 1.0f / (1.0f + __expf(-x));
}

// Fused kernel: blocks 0..337 sum sigmoid(obj)^2 over their 256 cells (5 anchors
// each, 5 independent loads/thread for MLP); block 338 does all per-target work.
__global__ __launch_bounds__(256) void fused_kernel(
        const float* __restrict__ pred, const float* __restrict__ tgt,
        float* __restrict__ ws) {
    if (blockIdx.x < NCONFBLK) {
        // ---- conf^2 partial over 256 consecutive cells ----
        int cell = blockIdx.x * 256 + threadIdx.x;           // < 86528
        const float* p = pred + (size_t)cell * PD_;
        float v = 0.0f;
        #pragma unroll
        for (int a = 0; a < A_; ++a) {
            float c = sigmoidf_(p[a * 85 + 4]);
            v += c * c;
        }
        #pragma unroll
        for (int off = 32; off > 0; off >>= 1)
            v += __shfl_down(v, off, 64);
        __shared__ float lds[4];
        int lane = threadIdx.x & 63;
        int wv = threadIdx.x >> 6;
        if (lane == 0) lds[wv] = v;
        __syncthreads();
        if (threadIdx.x == 0)
            ws[blockIdx.x] = lds[0] + lds[1] + lds[2] + lds[3];
    } else {
        // ---- per-target terms: wave w handles batches 8w..8w+7, lane = target ----
        const int lane = threadIdx.x & 63;
        const int wv = threadIdx.x >> 6;
        __shared__ int cellids[4][T_];
        __shared__ float wsum[4][4];

        float a_off = 0.f, a_scale = 0.f, a_obj = 0.f, a_c2 = 0.f;  // lane-0 accum

        for (int it = 0; it < 8; ++it) {
            const int b = wv * 8 + it;
            const int t = lane;
            const bool active = (t < T_);

            float gx = 0.f, gy = 0.f, gw = 0.f, gh = 0.f;
            float baw = 1.f, bah = 1.f;
            int best_a = 0, gi = 0, gj = 0;

            if (active) {
                const float* tp = tgt + ((size_t)b * T_ + t) * 5;
                gx = tp[0]; gy = tp[1]; gw = tp[2]; gh = tp[3];
                float gtw = gw * S_, gth = gh * S_;
                float best = -1.0f;
                #pragma unroll
                for (int a = 0; a < A_; ++a) {
                    float aw = c_anchors[2 * a], ah = c_anchors[2 * a + 1];
                    float inter = fminf(gtw, aw) * fminf(gth, ah);
                    float uni = gtw * gth + aw * ah - inter;
                    float iou = (uni > 0.0f) ? (inter / uni) : 0.0f;
                    if (iou > best) { best = iou; best_a = a; baw = aw; bah = ah; }
                }
                gi = (int)(gx * S_);   // truncation == floor (positive)
                gj = (int)(gy * S_);
                cellids[wv][t] = (best_a * S_ + gj) * S_ + gi;
            }
            __syncthreads();

            // last-target-wins dedupe (matches sequential scatter semantics)
            bool winner = active;
            if (active) {
                int myid = cellids[wv][t];
                for (int u = t + 1; u < T_; ++u)
                    if (cellids[wv][u] == myid) { winner = false; break; }
            }

            float s_off = 0.f, s_scale = 0.f, s_obj = 0.f, s_c2 = 0.f;
            if (winner) {
                float gtw = gw * S_, gth = gh * S_;
                const float* p = pred + (((size_t)b * S_ + gj) * S_ + gi) * PD_ + best_a * 85;
                float tx = p[0], ty = p[1], tw = p[2], th = p[3], to = p[4];

                float pbx = sigmoidf_(tx), pby = sigmoidf_(ty);
                float pbw = __expf(tw) * baw, pbh = __expf(th) * bah;
                float ggx = gx * S_ - (float)gi, ggy = gy * S_ - (float)gj;

                float cx1 = ggx + (float)gi, cy1 = ggy + (float)gj;
                float cx2 = pbx + (float)gi, cy2 = pby + (float)gj;
                float ix = fmaxf(0.0f, fminf(cx1 + gtw * 0.5f, cx2 + pbw * 0.5f)
                                     - fmaxf(cx1 - gtw * 0.5f, cx2 - pbw * 0.5f));
                float iy = fmaxf(0.0f, fminf(cy1 + gth * 0.5f, cy2 + pbh * 0.5f)
                                     - fmaxf(cy1 - gth * 0.5f, cy2 - pbh * 0.5f));
                float inter = ix * iy;
                float uni = gtw * gth + pbw * pbh - inter;
                float iou = (uni > 0.0f) ? (inter / uni) : 0.0f;

                float conf = sigmoidf_(to);

                s_off = (pbx - ggx) * (pbx - ggx) + (pby - ggy) * (pby - ggy);
                const float eps = 1e-6f;
                float dw = sqrtf(pbw + eps) - sqrtf(gtw + eps);
                float dh = sqrtf(pbh + eps) - sqrtf(gth + eps);
                s_scale = dw * dw + dh * dh;
                s_obj = (iou - conf) * (iou - conf);
                s_c2 = conf * conf;    // to subtract from the all-cells sum
            }

            #pragma unroll
            for (int off = 32; off > 0; off >>= 1) {
                s_off   += __shfl_down(s_off,   off, 64);
                s_scale += __shfl_down(s_scale, off, 64);
                s_obj   += __shfl_down(s_obj,   off, 64);
                s_c2    += __shfl_down(s_c2,    off, 64);
            }
            if (lane == 0) { a_off += s_off; a_scale += s_scale; a_obj += s_obj; a_c2 += s_c2; }
            __syncthreads();   // protect cellids before next iteration's overwrite
        }

        if (lane == 0) {
            wsum[wv][0] = a_off; wsum[wv][1] = a_scale;
            wsum[wv][2] = a_obj; wsum[wv][3] = a_c2;
        }
        __syncthreads();
        if (threadIdx.x == 0) {
            float o = 0.f, s = 0.f, ob = 0.f, c2 = 0.f;
            #pragma unroll
            for (int w = 0; w < 4; ++w) {
                o += wsum[w][0]; s += wsum[w][1]; ob += wsum[w][2]; c2 += wsum[w][3];
            }
            ws[NCONFBLK + 0] = o;  ws[NCONFBLK + 1] = s;
            ws[NCONFBLK + 2] = ob; ws[NCONFBLK + 3] = c2;
        }
    }
}

// Finalize: one wave reduces the 338 conf partials and composes the 3 outputs.
// (Kernel boundary provides the device-wide sync; no atomics/fences needed.)
__global__ __launch_bounds__(64) void finalize_kernel(
        const float* __restrict__ ws, float* __restrict__ out) {
    float v = 0.0f;
    for (int i = threadIdx.x; i < NCONFBLK; i += 64) v += ws[i];
    #pragma unroll
    for (int off = 32; off > 0; off >>= 1)
        v += __shfl_down(v, off, 64);
    if (threadIdx.x == 0) {
        float sum_all = v;
        float s_off = ws[NCONFBLK + 0], s_scale = ws[NCONFBLK + 1];
        float s_obj = ws[NCONFBLK + 2], s_c2w  = ws[NCONFBLK + 3];
        float loss_coord = 5.0f * (s_off + s_scale);       // offset+scale, each *5
        float loss_no_obj = 0.5f * (sum_all - s_c2w);
        float loss_obj = s_obj;
        out[0] = 5.0f * loss_coord + loss_obj + 0.5f * loss_no_obj;  // lambdas applied twice, per ref
        out[1] = loss_coord;
        out[2] = loss_obj + loss_no_obj;
    }
}

extern "C" void kernel_launch(void* const* d_in, const int* in_sizes, int n_in,
                              void* d_out, int out_size, void* d_ws, size_t ws_size,
                              hipStream_t stream) {
    const float* pred = (const float*)d_in[0];   // [32,52,52,425]
    const float* tgt  = (const float*)d_in[1];   // [32,50,5]
    float* out = (float*)d_out;                  // 3 scalars
    float* ws  = (float*)d_ws;                   // 342 floats used

    fused_kernel<<<NCONFBLK + 1, 256, 0, stream>>>(pred, tgt, ws);
    finalize_kernel<<<1, 64, 0, stream>>>(ws, out);
}